// Round 4
// baseline (114.287 us; speedup 1.0000x reference)
//
#include <hip/hip_runtime.h>
#include <math.h>

#define PIXELS 16384   // 4*64*64
#define C      128
#define KS     7
#define HEADS  4
#define HD     32      // head dim
#define QSCALE 0.17677669529663687f  // 32^-0.5

typedef __bf16 bf16x8 __attribute__((ext_vector_type(8)));
typedef __bf16 bf16x2 __attribute__((ext_vector_type(2)));
typedef float  f32x4  __attribute__((ext_vector_type(4)));
typedef float  f32x2  __attribute__((ext_vector_type(2)));

__device__ inline unsigned short f2bf(float f) {
    unsigned int u = __builtin_bit_cast(unsigned int, f);
    u += 0x7FFFu + ((u >> 16) & 1u);          // RNE
    return (unsigned short)(u >> 16);
}
__device__ inline float bflo(unsigned int u) {
    return __builtin_bit_cast(float, u << 16);
}
__device__ inline float bfhi(unsigned int u) {
    return __builtin_bit_cast(float, u & 0xFFFF0000u);
}

// ---------------------------------------------------------------------------
// GEMM 1 (prep folded in): B tiles staged straight from qkv_w/g1_w f32 with
// transpose-during-LDS-write.  Thread owns k-pair {2kp,2kp+1} x 16 n:
//   reads = 2 x 64B contiguous row segments (coalesced),
//   writes = 16 x b32 (k-even|k-odd packed), banks 2-way aliased (free, m136).
// Bias read directly from qkv_b/g1_b.  prep_kernel eliminated.
// ---------------------------------------------------------------------------
__global__ __launch_bounds__(256) void gemm_qkvh(
    const float* __restrict__ x,
    const float* __restrict__ qkv_w, const float* __restrict__ qkv_b,
    const float* __restrict__ g1_w, const float* __restrict__ g1_b,
    const float* __restrict__ g2_w, const float* __restrict__ g2_b,
    unsigned short* __restrict__ qkvb, float* __restrict__ gate)
{
    __shared__ __align__(16) unsigned short As[64*128];   // 16 KB
    __shared__ __align__(16) unsigned short Bs[64*128];   // 16 KB
    __shared__ __align__(16) unsigned short Cs[64*64];    // 8 KB epilogue/gate
    const int grp = blockIdx.x;
    const int ntBeg = grp ? 4 : 0, ntEnd = grp ? 7 : 4;
    const int m0 = blockIdx.y * 64;
    const int tid = threadIdx.x;

#pragma unroll
    for (int it = 0; it < 4; it++) {
        int idx = tid + it*256, row = idx >> 4, c = idx & 15;
        const float* src = x + (size_t)(m0+row)*128 + c*8;
        float4 a = *(const float4*)src;
        float4 b2 = *(const float4*)(src + 4);
        uint4 v;
        v.x = (unsigned int)f2bf(a.x)  | ((unsigned int)f2bf(a.y)  << 16);
        v.y = (unsigned int)f2bf(a.z)  | ((unsigned int)f2bf(a.w)  << 16);
        v.z = (unsigned int)f2bf(b2.x) | ((unsigned int)f2bf(b2.y) << 16);
        v.w = (unsigned int)f2bf(b2.z) | ((unsigned int)f2bf(b2.w) << 16);
        *(uint4*)(As + row*128 + ((c ^ (row&7)) << 3)) = v;
    }

    const int wave = tid >> 6, lane = tid & 63;
    const int l15 = lane & 15, quad = lane >> 4;
    const int wm = (wave & 1) * 32, wn = (wave >> 1) * 32;

    // transpose-staging decomposition (constant per thread)
    const int kp = tid >> 2;          // k-pair: k = 2kp, 2kp+1  (0..63 -> k<128)
    const int nc = (tid & 3) * 16;    // n-chunk base (0..48)
    const int bchunk = kp >> 2;       // (2kp)>>3: 16-bf16 chunk index
    const int boff = 2 * (kp & 3);    // (2kp)&7: short offset within chunk

    for (int nt = ntBeg; nt < ntEnd; nt++) {
        const int n0 = nt * 64;
        {
            // B[n][k] = w[k][n]; w = qkv_w rows of 384 (nt<6) or g1_w rows of 64
            const float* r0 = (nt < 6) ? (qkv_w + (size_t)(2*kp)*384 + n0 + nc)
                                       : (g1_w  + (size_t)(2*kp)*64  + nc);
            const float* r1 = r0 + ((nt < 6) ? 384 : 64);
            float e0[16], e1[16];
#pragma unroll
            for (int q = 0; q < 4; q++) {
                float4 a = ((const float4*)r0)[q];
                float4 b2 = ((const float4*)r1)[q];
                e0[q*4+0]=a.x; e0[q*4+1]=a.y; e0[q*4+2]=a.z; e0[q*4+3]=a.w;
                e1[q*4+0]=b2.x; e1[q*4+1]=b2.y; e1[q*4+2]=b2.z; e1[q*4+3]=b2.w;
            }
#pragma unroll
            for (int i = 0; i < 16; i++) {
                int n = nc + i;
                unsigned int w = (unsigned int)f2bf(e0[i])
                               | ((unsigned int)f2bf(e1[i]) << 16);
                *(unsigned int*)(Bs + n*128 + ((bchunk ^ (n&7)) << 3) + boff) = w;
            }
        }
        __syncthreads();   // sync1

        f32x4 acc[2][2] = {};
#pragma unroll
        for (int ks = 0; ks < 4; ks++) {
            bf16x8 af[2], bq[2];
#pragma unroll
            for (int mt = 0; mt < 2; mt++) {
                int m = wm + mt*16 + l15;
                af[mt] = *(const bf16x8*)(As + m*128 + (((ks*4+quad) ^ (m&7)) << 3));
            }
#pragma unroll
            for (int ntl = 0; ntl < 2; ntl++) {
                int n = wn + ntl*16 + l15;
                bq[ntl] = *(const bf16x8*)(Bs + n*128 + (((ks*4+quad) ^ (n&7)) << 3));
            }
#pragma unroll
            for (int mt = 0; mt < 2; mt++)
#pragma unroll
                for (int ntl = 0; ntl < 2; ntl++)
                    acc[mt][ntl] = __builtin_amdgcn_mfma_f32_16x16x32_bf16(
                        af[mt], bq[ntl], acc[mt][ntl], 0, 0, 0);
        }

        if (nt < 6) {
#pragma unroll
            for (int ntl = 0; ntl < 2; ntl++) {
                int nl = wn + ntl*16 + l15;
                int ng = n0 + nl;
                float qs = (ng < 128) ? QSCALE : 1.0f;
                float bv = qkv_b[ng];
#pragma unroll
                for (int mt = 0; mt < 2; mt++)
#pragma unroll
                    for (int r = 0; r < 4; r++) {
                        int ml = wm + mt*16 + quad*4 + r;
                        Cs[ml*64 + nl] = f2bf((acc[mt][ntl][r] + bv) * qs);
                    }
            }
            __syncthreads();   // sync2
            int row = tid >> 2, part = tid & 3;
            uint4 a = *(const uint4*)(Cs + row*64 + part*16);
            uint4 b = *(const uint4*)(Cs + row*64 + part*16 + 8);
            unsigned short* dst = qkvb + (size_t)(m0+row)*384 + n0 + part*16;
            *(uint4*)dst = a;
            *(uint4*)(dst + 8) = b;
        } else {
            float* gpart = (float*)Cs;   // [2][64] f32
            float rs[2][4];
#pragma unroll
            for (int mt = 0; mt < 2; mt++)
#pragma unroll
                for (int r = 0; r < 4; r++) rs[mt][r] = 0.0f;
#pragma unroll
            for (int ntl = 0; ntl < 2; ntl++) {
                int nl = wn + ntl*16 + l15;
                float bv = g1_b[nl];
                float gw = g2_w[nl];
#pragma unroll
                for (int mt = 0; mt < 2; mt++)
#pragma unroll
                    for (int r = 0; r < 4; r++) {
                        float h = acc[mt][ntl][r] + bv;
                        rs[mt][r] += fmaxf(h, 0.0f) * gw;
                    }
            }
#pragma unroll
            for (int off = 1; off <= 8; off <<= 1)
#pragma unroll
                for (int mt = 0; mt < 2; mt++)
#pragma unroll
                    for (int r = 0; r < 4; r++)
                        rs[mt][r] += __shfl_xor(rs[mt][r], off);
            if (l15 == 0) {
#pragma unroll
                for (int mt = 0; mt < 2; mt++)
#pragma unroll
                    for (int r = 0; r < 4; r++)
                        gpart[(wave >> 1)*64 + wm + mt*16 + quad*4 + r] = rs[mt][r];
            }
            __syncthreads();
            if (tid < 64) {
                float g = gpart[tid] + gpart[64 + tid] + g2_b[0];
                gate[m0 + tid] = 1.0f / (1.0f + __expf(-g));
            }
        }
    }
}

// ---------------------------------------------------------------------------
// FUSED attn + proj GEMM + gate + residual (r3-proven structure), now with:
//  - proj-weight Bs staged from proj_w f32 (transpose-during-write, early:
//    overlaps the attn phase; own LDS region, no reuse bubble at the tail)
//  - XCD-locality remap: ti = bid&7 -> each XCD (round-robin dispatch) owns
//    one tile-row strip per batch; KV working set/XCD ~1.8MB < 4MB L2.
// LDS: kvs 103,488 | rpb 2,704 | As 16,384 | Bs 32,768 = 155,344 B.
// Cs (32KB f32) reuses the dead kvs region after attn.
// ---------------------------------------------------------------------------
#define ATTN_PROJ_LDS (196*264*2 + 676*4 + 64*128*2 + 128*128*2)   // 155,344

__global__ __launch_bounds__(512) void attn_proj(
    const unsigned short* __restrict__ qkvb, const float* __restrict__ rpb,
    const float* __restrict__ proj_w, const float* __restrict__ proj_b,
    const float* __restrict__ gate, const float* __restrict__ x,
    float* __restrict__ out)
{
    extern __shared__ __align__(16) unsigned char dynsmem[];
    unsigned short* kvs = (unsigned short*)dynsmem;                    // 196*264
    float* rpb_lds = (float*)(dynsmem + 196*264*2);                    // 676 f32
    unsigned short* As = (unsigned short*)(dynsmem + 196*264*2 + 676*4);
    unsigned short* Bs = (unsigned short*)(dynsmem + 196*264*2 + 676*4 + 64*128*2);
    float* Cs = (float*)dynsmem;                                       // reuse kvs

    const int bid = blockIdx.x;
    // XCD-aware remap (bijective): consecutive bids round-robin XCDs, so
    // bid&7 pins the tile-row to one XCD's L2.
    const int ti = bid & 7;
    const int rest = bid >> 3;            // 0..31
    const int b = rest >> 3;              // batch 0..3
    const int tj = rest & 7;
    const int ti0 = ti * 8, tj0 = tj * 8;
    int wr0 = ti0 - 3; wr0 = wr0 < 0 ? 0 : (wr0 > 50 ? 50 : wr0);
    int wc0 = tj0 - 3; wc0 = wc0 < 0 ? 0 : (wc0 > 50 ? 50 : wc0);

    const int tid = threadIdx.x;
    const int wave = tid >> 6, lane = tid & 63;
    const int h = wave & 3;               // head
    const int pg = wave >> 2;             // pixel group (rows 0-3 / 4-7)
    const int half = lane >> 5;           // dim half: 0 = dims 0..15
    const int p5 = lane & 31;
    const int pi = pg * 4 + (p5 >> 3), pj = p5 & 7;
    const int i = ti0 + pi, j = tj0 + pj;
    int sh = i - 3; sh = sh < 0 ? 0 : (sh > 57 ? 57 : sh);
    int sw = j - 3; sw = sw < 0 ? 0 : (sw > 57 ? 57 : sw);
    const int dr = sh - wr0, dc = sw - wc0;
    const size_t gp = (size_t)(((b << 6) + i) << 6) + j;

    // Q first: latency hides under staging
    unsigned int qu[8];
    const unsigned short* qptr = qkvb + gp * 384 + h * 32 + half * 16;
    *(uint4*)(qu + 0) = *(const uint4*)(qptr + 0);
    *(uint4*)(qu + 4) = *(const uint4*)(qptr + 8);

    float rpb_v[2];
#pragma unroll
    for (int t = 0; t < 2; t++) {
        int idx = tid + t * 512;
        rpb_v[t] = (idx < 676) ? rpb[idx] : 0.0f;
    }

    // stage K/V all 4 heads: 196 pos x 32 chunks (16B); src & dst contiguous.
    for (int idx = tid; idx < 196 * 32; idx += 512) {
        int pos = idx >> 5, t = idx & 31;
        int wr = pos / 14, wc = pos - wr * 14;
        size_t gpos = (size_t)(((b << 6) + (wr0 + wr)) << 6) + (wc0 + wc);
        uint4 v = *(const uint4*)(qkvb + gpos * 384 + 128 + t * 8);
        *(uint4*)(kvs + pos * 264 + t * 8) = v;
    }

    // stage Bs[n][k] = proj_w[k][n] (transpose-during-write), early.
    // thread: k-pair {2kp,2kp+1}, 16 n.  coalesced 64B row reads; b32 writes.
    {
        const int kp = tid >> 3;          // 0..63
        const int nc = (tid & 7) * 16;    // 0..112
        const int bchunk = kp >> 2;
        const int boff = 2 * (kp & 3);
        const float* r0 = proj_w + (size_t)(2*kp)*128 + nc;
        const float* r1 = r0 + 128;
        float e0[16], e1[16];
#pragma unroll
        for (int q = 0; q < 4; q++) {
            float4 a = ((const float4*)r0)[q];
            float4 b2 = ((const float4*)r1)[q];
            e0[q*4+0]=a.x; e0[q*4+1]=a.y; e0[q*4+2]=a.z; e0[q*4+3]=a.w;
            e1[q*4+0]=b2.x; e1[q*4+1]=b2.y; e1[q*4+2]=b2.z; e1[q*4+3]=b2.w;
        }
#pragma unroll
        for (int q = 0; q < 16; q++) {
            int n = nc + q;
            unsigned int w = (unsigned int)f2bf(e0[q])
                           | ((unsigned int)f2bf(e1[q]) << 16);
            *(unsigned int*)(Bs + n*128 + ((bchunk ^ (n&7)) << 3) + boff) = w;
        }
    }
#pragma unroll
    for (int t = 0; t < 2; t++) {
        int idx = tid + t * 512;
        if (idx < 676) rpb_lds[idx] = rpb_v[t];
    }
    __syncthreads();

    f32x2 acc2[8];
#pragma unroll
    for (int p = 0; p < 8; p++) acc2[p] = (f32x2){0.f, 0.f};
    float ssum = 0.0f;

    const float* rl = rpb_lds + h * 169;
    const int rbase = (sh - i + 6) * 13 + (sw - j + 6);
    const int hwbase = (dr * 14 + dc) * 264 + h * 32 + half * 16;

    for (int kr = 0; kr < 7; kr++) {
        const unsigned short* rowp = kvs + hwbase + kr * (14 * 264);
        const int ri = rbase + kr * 13;

        unsigned int ku[8], vu[8];
        *(uint4*)(ku + 0) = *(const uint4*)(rowp + 0);
        *(uint4*)(ku + 4) = *(const uint4*)(rowp + 8);
        *(uint4*)(vu + 0) = *(const uint4*)(rowp + 128);
        *(uint4*)(vu + 4) = *(const uint4*)(rowp + 136);

#pragma unroll
        for (int kc = 0; kc < 7; kc++) {
            unsigned int ku2[8], vu2[8];
            if (kc < 6) {   // prefetch next key while computing current
                const unsigned short* kpn = rowp + (kc + 1) * 264;
                *(uint4*)(ku2 + 0) = *(const uint4*)(kpn + 0);
                *(uint4*)(ku2 + 4) = *(const uint4*)(kpn + 8);
                *(uint4*)(vu2 + 0) = *(const uint4*)(kpn + 128);
                *(uint4*)(vu2 + 4) = *(const uint4*)(kpn + 136);
            }

            float s0 = 0.0f, s1 = 0.0f;
#if __has_builtin(__builtin_amdgcn_fdot2_f32_bf16)
#pragma unroll
            for (int p = 0; p < 4; p++) {
                s0 = __builtin_amdgcn_fdot2_f32_bf16(
                        __builtin_bit_cast(bf16x2, qu[p]),
                        __builtin_bit_cast(bf16x2, ku[p]), s0, false);
                s1 = __builtin_amdgcn_fdot2_f32_bf16(
                        __builtin_bit_cast(bf16x2, qu[p+4]),
                        __builtin_bit_cast(bf16x2, ku[p+4]), s1, false);
            }
#else
#pragma unroll
            for (int p = 0; p < 4; p++) {
                s0 += bflo(qu[p])   * bflo(ku[p])   + bfhi(qu[p])   * bfhi(ku[p]);
                s1 += bflo(qu[p+4]) * bflo(ku[p+4]) + bfhi(qu[p+4]) * bfhi(ku[p+4]);
            }
#endif
            float s = s0 + s1;
            s += __shfl_xor(s, 32);            // combine dim-halves
            float e = __expf(s + rl[ri + kc]); // max-free: bounded scores
            ssum += e;

            f32x2 e2 = {e, e};
#pragma unroll
            for (int p = 0; p < 8; p++) {
                f32x2 v2 = {bflo(vu[p]), bfhi(vu[p])};
                acc2[p] += e2 * v2;
            }

            if (kc < 6) {
#pragma unroll
                for (int p = 0; p < 8; p++) { ku[p] = ku2[p]; vu[p] = vu2[p]; }
            }
        }
    }

    // write normalized attn out into As (GEMM swizzle layout)
    {
        const float inv = 1.0f / ssum;
        unsigned int o[8];
#pragma unroll
        for (int p = 0; p < 8; p++) {
            unsigned int lo = f2bf(acc2[p].x * inv);
            unsigned int hi = f2bf(acc2[p].y * inv);
            o[p] = lo | (hi << 16);
        }
        const int pix = pi * 8 + pj;
        const int c0 = h * 4 + half * 2;
        *(uint4*)(As + pix*128 + (((c0  ) ^ (pix&7)) << 3)) = *(const uint4*)(o + 0);
        *(uint4*)(As + pix*128 + (((c0+1) ^ (pix&7)) << 3)) = *(const uint4*)(o + 4);
    }
    __syncthreads();   // As complete; kvs reads done -> Cs region safe

    // proj GEMM: M=64, N=128, K=128.  8 waves = 2m x 4n.
    {
        const int l15 = lane & 15, quad = lane >> 4;
        const int wm = (wave & 1) * 32, wn = (wave >> 1) * 32;

        f32x4 acc[2][2] = {};
#pragma unroll
        for (int ks = 0; ks < 4; ks++) {
            bf16x8 af[2], bq[2];
#pragma unroll
            for (int mt = 0; mt < 2; mt++) {
                int m = wm + mt*16 + l15;
                af[mt] = *(const bf16x8*)(As + m*128 + (((ks*4+quad) ^ (m&7)) << 3));
            }
#pragma unroll
            for (int ntl = 0; ntl < 2; ntl++) {
                int n = wn + ntl*16 + l15;
                bq[ntl] = *(const bf16x8*)(Bs + n*128 + (((ks*4+quad) ^ (n&7)) << 3));
            }
#pragma unroll
            for (int mt = 0; mt < 2; mt++)
#pragma unroll
                for (int ntl = 0; ntl < 2; ntl++)
                    acc[mt][ntl] = __builtin_amdgcn_mfma_f32_16x16x32_bf16(
                        af[mt], bq[ntl], acc[mt][ntl], 0, 0, 0);
        }

#pragma unroll
        for (int ntl = 0; ntl < 2; ntl++) {
            int nl = wn + ntl*16 + l15;
            float bv = proj_b[nl];
#pragma unroll
            for (int mt = 0; mt < 2; mt++)
#pragma unroll
                for (int r = 0; r < 4; r++) {
                    int ml = wm + mt*16 + quad*4 + r;
                    Cs[ml*128 + nl] = acc[mt][ntl][r] + bv;
                }
        }
    }
    __syncthreads();

    // epilogue: out = Cs * gate + x
    {
        int pix = tid >> 3, part = tid & 7;
        int gi = ti0 + (pix >> 3), gj = tj0 + (pix & 7);
        size_t gr = (size_t)(((b << 6) + gi) << 6) + gj;
        float gv = gate[gr];
        const float* xr = x + gr*128 + part*16;
        float* orow = out + gr*128 + part*16;
#pragma unroll
        for (int q = 0; q < 4; q++) {
            float4 cv = *(const float4*)(Cs + pix*128 + part*16 + q*4);
            float4 xv = *(const float4*)(xr + q*4);
            float4 o;
            o.x = cv.x * gv + xv.x; o.y = cv.y * gv + xv.y;
            o.z = cv.z * gv + xv.z; o.w = cv.w * gv + xv.w;
            *(float4*)(orow + q*4) = o;
        }
    }
}

// ---------------------------------------------------------------------------
extern "C" void kernel_launch(void* const* d_in, const int* in_sizes, int n_in,
                              void* d_out, int out_size, void* d_ws, size_t ws_size,
                              hipStream_t stream)
{
    const float* x      = (const float*)d_in[0];
    const float* qkv_w  = (const float*)d_in[1];
    const float* qkv_b  = (const float*)d_in[2];
    const float* proj_w = (const float*)d_in[3];
    const float* proj_b = (const float*)d_in[4];
    const float* rpb    = (const float*)d_in[5];
    const float* g1_w   = (const float*)d_in[6];
    const float* g1_b   = (const float*)d_in[7];
    const float* g2_w   = (const float*)d_in[8];
    const float* g2_b   = (const float*)d_in[9];
    float* out = (float*)d_out;

    float* ws        = (float*)d_ws;
    float* gate      = ws;                          // 16384 f32
    unsigned short* qkvb = (unsigned short*)(gate + 16384);  // 16384*384 bf16

    (void)in_sizes; (void)n_in; (void)out_size; (void)ws_size;

    // one-time host-only opt-in for 155.3 KB dynamic LDS (capture-safe)
    static int lds_ok = -1;
    if (lds_ok < 0) {
        hipError_t ae = hipFuncSetAttribute(
            (const void*)attn_proj,
            hipFuncAttributeMaxDynamicSharedMemorySize, ATTN_PROJ_LDS);
        lds_ok = (ae == hipSuccess) ? 1 : 0;
    }

    gemm_qkvh<<<dim3(2, 256), 256, 0, stream>>>(x, qkv_w, qkv_b, g1_w, g1_b,
                                                g2_w, g2_b, qkvb, gate);
    attn_proj<<<256, 512, ATTN_PROJ_LDS, stream>>>(qkvb, rpb, proj_w, proj_b,
                                                   gate, x, out);
}

// Round 5
// 110.242 us; speedup vs baseline: 1.0367x; 1.0367x over previous
//
#include <hip/hip_runtime.h>
#include <math.h>

#define PIXELS 16384   // 4*64*64
#define C      128
#define KS     7
#define HEADS  4
#define HD     32      // head dim
#define QSCALE 0.17677669529663687f  // 32^-0.5

typedef __bf16 bf16x8 __attribute__((ext_vector_type(8)));
typedef __bf16 bf16x2 __attribute__((ext_vector_type(2)));
typedef float  f32x4  __attribute__((ext_vector_type(4)));
typedef float  f32x2  __attribute__((ext_vector_type(2)));

__device__ inline unsigned short f2bf(float f) {
    unsigned int u = __builtin_bit_cast(unsigned int, f);
    u += 0x7FFFu + ((u >> 16) & 1u);          // RNE
    return (unsigned short)(u >> 16);
}
__device__ inline float bflo(unsigned int u) {
    return __builtin_bit_cast(float, u << 16);
}
__device__ inline float bfhi(unsigned int u) {
    return __builtin_bit_cast(float, u & 0xFFFF0000u);
}

// ---------------------------------------------------------------------------
// prep (weights only): wT[448][128] = [qkv_w|g1_w]^T bf16;
// pT[128][128] = proj_w^T bf16; bias_ext[448].  grid 73 x 256.
// (One-time transpose+convert amortized over 512 consumer blocks — the r4
// per-block fold of this work was a measured 3us regression.)
// ---------------------------------------------------------------------------
__global__ __launch_bounds__(256) void prep_kernel(
    const float* __restrict__ qkv_w, const float* __restrict__ g1_w,
    const float* __restrict__ qkv_b, const float* __restrict__ g1_b,
    const float* __restrict__ proj_w,
    unsigned short* __restrict__ wT, unsigned short* __restrict__ pT,
    float* __restrict__ bias_ext)
{
    const int blk = blockIdx.x, tid = threadIdx.x;
    if (blk < 56) {
        int n = blk * 8 + (tid >> 5);
        int kq = tid & 31;
        float f0, f1, f2, f3;
        if (n < 384) {
            f0 = qkv_w[(kq*4+0)*384 + n]; f1 = qkv_w[(kq*4+1)*384 + n];
            f2 = qkv_w[(kq*4+2)*384 + n]; f3 = qkv_w[(kq*4+3)*384 + n];
        } else {
            int nn = n - 384;
            f0 = g1_w[(kq*4+0)*64 + nn]; f1 = g1_w[(kq*4+1)*64 + nn];
            f2 = g1_w[(kq*4+2)*64 + nn]; f3 = g1_w[(kq*4+3)*64 + nn];
        }
        ushort4 o; o.x = f2bf(f0); o.y = f2bf(f1); o.z = f2bf(f2); o.w = f2bf(f3);
        *(ushort4*)(wT + n*128 + kq*4) = o;
    } else if (blk < 72) {
        int n = (blk - 56) * 8 + (tid >> 5);
        int kq = tid & 31;
        ushort4 o;
        o.x = f2bf(proj_w[(kq*4+0)*128 + n]);
        o.y = f2bf(proj_w[(kq*4+1)*128 + n]);
        o.z = f2bf(proj_w[(kq*4+2)*128 + n]);
        o.w = f2bf(proj_w[(kq*4+3)*128 + n]);
        *(ushort4*)(pT + n*128 + kq*4) = o;
    } else {
        for (int idx = tid; idx < 448; idx += 256)
            bias_ext[idx] = (idx < 384) ? qkv_b[idx] : g1_b[idx - 384];
    }
}

// ---------------------------------------------------------------------------
// GEMM 1 (fused): qkvb[pix][384] bf16, N-tile loop, gate fused.  (r3 proven)
// ---------------------------------------------------------------------------
__global__ __launch_bounds__(256) void gemm_qkvh_fused(
    const float* __restrict__ x, const unsigned short* __restrict__ wT,
    const float* __restrict__ bias_ext, const float* __restrict__ g2_w,
    const float* __restrict__ g2_b, unsigned short* __restrict__ qkvb,
    float* __restrict__ gate)
{
    __shared__ __align__(16) unsigned short As[64*128];
    __shared__ __align__(16) unsigned short Bs[64*128];
    __shared__ __align__(16) unsigned short Cs[64*64];
    const int grp = blockIdx.x;
    const int ntBeg = grp ? 4 : 0, ntEnd = grp ? 7 : 4;
    const int m0 = blockIdx.y * 64;
    const int tid = threadIdx.x;

#pragma unroll
    for (int it = 0; it < 4; it++) {
        int idx = tid + it*256, row = idx >> 4, c = idx & 15;
        const float* src = x + (size_t)(m0+row)*128 + c*8;
        float4 a = *(const float4*)src;
        float4 b2 = *(const float4*)(src + 4);
        uint4 v;
        v.x = (unsigned int)f2bf(a.x)  | ((unsigned int)f2bf(a.y)  << 16);
        v.y = (unsigned int)f2bf(a.z)  | ((unsigned int)f2bf(a.w)  << 16);
        v.z = (unsigned int)f2bf(b2.x) | ((unsigned int)f2bf(b2.y) << 16);
        v.w = (unsigned int)f2bf(b2.z) | ((unsigned int)f2bf(b2.w) << 16);
        *(uint4*)(As + row*128 + ((c ^ (row&7)) << 3)) = v;
    }

    const int wave = tid >> 6, lane = tid & 63;
    const int l15 = lane & 15, quad = lane >> 4;
    const int wm = (wave & 1) * 32, wn = (wave >> 1) * 32;

    for (int nt = ntBeg; nt < ntEnd; nt++) {
        const int n0 = nt * 64;
#pragma unroll
        for (int it = 0; it < 4; it++) {
            int idx = tid + it*256, row = idx >> 4, c = idx & 15;
            uint4 v = *(const uint4*)(wT + (size_t)(n0+row)*128 + c*8);
            *(uint4*)(Bs + row*128 + ((c ^ (row&7)) << 3)) = v;
        }
        __syncthreads();   // sync1

        f32x4 acc[2][2] = {};
#pragma unroll
        for (int ks = 0; ks < 4; ks++) {
            bf16x8 af[2], bq[2];
#pragma unroll
            for (int mt = 0; mt < 2; mt++) {
                int m = wm + mt*16 + l15;
                af[mt] = *(const bf16x8*)(As + m*128 + (((ks*4+quad) ^ (m&7)) << 3));
            }
#pragma unroll
            for (int ntl = 0; ntl < 2; ntl++) {
                int n = wn + ntl*16 + l15;
                bq[ntl] = *(const bf16x8*)(Bs + n*128 + (((ks*4+quad) ^ (n&7)) << 3));
            }
#pragma unroll
            for (int mt = 0; mt < 2; mt++)
#pragma unroll
                for (int ntl = 0; ntl < 2; ntl++)
                    acc[mt][ntl] = __builtin_amdgcn_mfma_f32_16x16x32_bf16(
                        af[mt], bq[ntl], acc[mt][ntl], 0, 0, 0);
        }

        if (nt < 6) {
#pragma unroll
            for (int ntl = 0; ntl < 2; ntl++) {
                int nl = wn + ntl*16 + l15;
                int ng = n0 + nl;
                float qs = (ng < 128) ? QSCALE : 1.0f;
                float bv = bias_ext[ng];
#pragma unroll
                for (int mt = 0; mt < 2; mt++)
#pragma unroll
                    for (int r = 0; r < 4; r++) {
                        int ml = wm + mt*16 + quad*4 + r;
                        Cs[ml*64 + nl] = f2bf((acc[mt][ntl][r] + bv) * qs);
                    }
            }
            __syncthreads();   // sync2
            int row = tid >> 2, part = tid & 3;
            uint4 a = *(const uint4*)(Cs + row*64 + part*16);
            uint4 b = *(const uint4*)(Cs + row*64 + part*16 + 8);
            unsigned short* dst = qkvb + (size_t)(m0+row)*384 + n0 + part*16;
            *(uint4*)dst = a;
            *(uint4*)(dst + 8) = b;
        } else {
            float* gpart = (float*)Cs;
            float rs[2][4];
#pragma unroll
            for (int mt = 0; mt < 2; mt++)
#pragma unroll
                for (int r = 0; r < 4; r++) rs[mt][r] = 0.0f;
#pragma unroll
            for (int ntl = 0; ntl < 2; ntl++) {
                int nl = wn + ntl*16 + l15;
                float bv = bias_ext[384 + nl];
                float gw = g2_w[nl];
#pragma unroll
                for (int mt = 0; mt < 2; mt++)
#pragma unroll
                    for (int r = 0; r < 4; r++) {
                        float h = acc[mt][ntl][r] + bv;
                        rs[mt][r] += fmaxf(h, 0.0f) * gw;
                    }
            }
#pragma unroll
            for (int off = 1; off <= 8; off <<= 1)
#pragma unroll
                for (int mt = 0; mt < 2; mt++)
#pragma unroll
                    for (int r = 0; r < 4; r++)
                        rs[mt][r] += __shfl_xor(rs[mt][r], off);
            if (l15 == 0) {
#pragma unroll
                for (int mt = 0; mt < 2; mt++)
#pragma unroll
                    for (int r = 0; r < 4; r++)
                        gpart[(wave >> 1)*64 + wm + mt*16 + quad*4 + r] = rs[mt][r];
            }
            __syncthreads();
            if (tid < 64) {
                float g = gpart[tid] + gpart[64 + tid] + g2_b[0];
                gate[m0 + tid] = 1.0f / (1.0f + __expf(-g));
            }
        }
    }
}

// ---------------------------------------------------------------------------
// FUSED attn + proj GEMM + gate + residual (r3-proven structure) with ONE
// change vs r3: Bs (= pT, bf16) is staged into its OWN LDS region EARLY,
// overlapping the attn phase — removes the serialized tail staging + barrier.
// LDS: kvs 103,488 | rpb 2,704 | As 16,384 | Bs 32,768 = 155,344 B (1 blk/CU,
// same occupancy as r3's 122.6KB).  Cs (32KB f32) reuses the dead kvs region.
// Tile map bid = b(4) x tile(64): bid&7 = tj -> each XCD already owns a
// tile-column strip per batch (round-robin dispatch) — no remap needed.
// ---------------------------------------------------------------------------
#define ATTN_PROJ_LDS (196*264*2 + 676*4 + 64*128*2 + 128*128*2)   // 155,344

__global__ __launch_bounds__(512) void attn_proj(
    const unsigned short* __restrict__ qkvb, const float* __restrict__ rpb,
    const unsigned short* __restrict__ pT, const float* __restrict__ proj_b,
    const float* __restrict__ gate, const float* __restrict__ x,
    float* __restrict__ out)
{
    extern __shared__ __align__(16) unsigned char dynsmem[];
    unsigned short* kvs = (unsigned short*)dynsmem;                    // 196*264
    float* rpb_lds = (float*)(dynsmem + 196*264*2);                    // 676 f32
    unsigned short* As = (unsigned short*)(dynsmem + 196*264*2 + 676*4);
    unsigned short* Bs = (unsigned short*)(dynsmem + 196*264*2 + 676*4 + 64*128*2);
    float* Cs = (float*)dynsmem;                                       // reuse kvs

    const int bid = blockIdx.x;
    const int b = bid >> 6;
    const int tile = bid & 63;            // 8 row-tiles x 8 col-tiles
    const int ti0 = (tile >> 3) * 8, tj0 = (tile & 7) * 8;
    int wr0 = ti0 - 3; wr0 = wr0 < 0 ? 0 : (wr0 > 50 ? 50 : wr0);
    int wc0 = tj0 - 3; wc0 = wc0 < 0 ? 0 : (wc0 > 50 ? 50 : wc0);

    const int tid = threadIdx.x;
    const int wave = tid >> 6, lane = tid & 63;
    const int h = wave & 3;               // head
    const int pg = wave >> 2;             // pixel group (rows 0-3 / 4-7)
    const int half = lane >> 5;           // dim half: 0 = dims 0..15
    const int p5 = lane & 31;
    const int pi = pg * 4 + (p5 >> 3), pj = p5 & 7;
    const int i = ti0 + pi, j = tj0 + pj;
    int sh = i - 3; sh = sh < 0 ? 0 : (sh > 57 ? 57 : sh);
    int sw = j - 3; sw = sw < 0 ? 0 : (sw > 57 ? 57 : sw);
    const int dr = sh - wr0, dc = sw - wc0;
    const size_t gp = (size_t)(((b << 6) + i) << 6) + j;

    // Q first: latency hides under staging
    unsigned int qu[8];
    const unsigned short* qptr = qkvb + gp * 384 + h * 32 + half * 16;
    *(uint4*)(qu + 0) = *(const uint4*)(qptr + 0);
    *(uint4*)(qu + 4) = *(const uint4*)(qptr + 8);

    float rpb_v[2];
#pragma unroll
    for (int t = 0; t < 2; t++) {
        int idx = tid + t * 512;
        rpb_v[t] = (idx < 676) ? rpb[idx] : 0.0f;
    }

    // stage K/V all 4 heads: 196 pos x 32 chunks (16B); src & dst contiguous.
    for (int idx = tid; idx < 196 * 32; idx += 512) {
        int pos = idx >> 5, t = idx & 31;
        int wr = pos / 14, wc = pos - wr * 14;
        size_t gpos = (size_t)(((b << 6) + (wr0 + wr)) << 6) + (wc0 + wc);
        uint4 v = *(const uint4*)(qkvb + gpos * 384 + 128 + t * 8);
        *(uint4*)(kvs + pos * 264 + t * 8) = v;
    }

    // stage Bs = pT (128x128 bf16, 32KB) EARLY: overlaps the attn phase.
#pragma unroll
    for (int it = 0; it < 4; it++) {
        int idx = tid + it*512, row = idx >> 4, c = idx & 15;
        uint4 v = *(const uint4*)(pT + (size_t)row*128 + c*8);
        *(uint4*)(Bs + row*128 + ((c ^ (row&7)) << 3)) = v;
    }
#pragma unroll
    for (int t = 0; t < 2; t++) {
        int idx = tid + t * 512;
        if (idx < 676) rpb_lds[idx] = rpb_v[t];
    }
    __syncthreads();

    f32x2 acc2[8];
#pragma unroll
    for (int p = 0; p < 8; p++) acc2[p] = (f32x2){0.f, 0.f};
    float ssum = 0.0f;

    const float* rl = rpb_lds + h * 169;
    const int rbase = (sh - i + 6) * 13 + (sw - j + 6);
    const int hwbase = (dr * 14 + dc) * 264 + h * 32 + half * 16;

    for (int kr = 0; kr < 7; kr++) {
        const unsigned short* rowp = kvs + hwbase + kr * (14 * 264);
        const int ri = rbase + kr * 13;

        unsigned int ku[8], vu[8];
        *(uint4*)(ku + 0) = *(const uint4*)(rowp + 0);
        *(uint4*)(ku + 4) = *(const uint4*)(rowp + 8);
        *(uint4*)(vu + 0) = *(const uint4*)(rowp + 128);
        *(uint4*)(vu + 4) = *(const uint4*)(rowp + 136);

#pragma unroll
        for (int kc = 0; kc < 7; kc++) {
            unsigned int ku2[8], vu2[8];
            if (kc < 6) {   // prefetch next key while computing current
                const unsigned short* kpn = rowp + (kc + 1) * 264;
                *(uint4*)(ku2 + 0) = *(const uint4*)(kpn + 0);
                *(uint4*)(ku2 + 4) = *(const uint4*)(kpn + 8);
                *(uint4*)(vu2 + 0) = *(const uint4*)(kpn + 128);
                *(uint4*)(vu2 + 4) = *(const uint4*)(kpn + 136);
            }

            float s0 = 0.0f, s1 = 0.0f;
#if __has_builtin(__builtin_amdgcn_fdot2_f32_bf16)
#pragma unroll
            for (int p = 0; p < 4; p++) {
                s0 = __builtin_amdgcn_fdot2_f32_bf16(
                        __builtin_bit_cast(bf16x2, qu[p]),
                        __builtin_bit_cast(bf16x2, ku[p]), s0, false);
                s1 = __builtin_amdgcn_fdot2_f32_bf16(
                        __builtin_bit_cast(bf16x2, qu[p+4]),
                        __builtin_bit_cast(bf16x2, ku[p+4]), s1, false);
            }
#else
#pragma unroll
            for (int p = 0; p < 4; p++) {
                s0 += bflo(qu[p])   * bflo(ku[p])   + bfhi(qu[p])   * bfhi(ku[p]);
                s1 += bflo(qu[p+4]) * bflo(ku[p+4]) + bfhi(qu[p+4]) * bfhi(ku[p+4]);
            }
#endif
            float s = s0 + s1;
            s += __shfl_xor(s, 32);            // combine dim-halves
            float e = __expf(s + rl[ri + kc]); // max-free: bounded scores
            ssum += e;

            f32x2 e2 = {e, e};
#pragma unroll
            for (int p = 0; p < 8; p++) {
                f32x2 v2 = {bflo(vu[p]), bfhi(vu[p])};
                acc2[p] += e2 * v2;
            }

            if (kc < 6) {
#pragma unroll
                for (int p = 0; p < 8; p++) { ku[p] = ku2[p]; vu[p] = vu2[p]; }
            }
        }
    }

    // write normalized attn out into As (GEMM swizzle layout)
    {
        const float inv = 1.0f / ssum;
        unsigned int o[8];
#pragma unroll
        for (int p = 0; p < 8; p++) {
            unsigned int lo = f2bf(acc2[p].x * inv);
            unsigned int hi = f2bf(acc2[p].y * inv);
            o[p] = lo | (hi << 16);
        }
        const int pix = pi * 8 + pj;
        const int c0 = h * 4 + half * 2;
        *(uint4*)(As + pix*128 + (((c0  ) ^ (pix&7)) << 3)) = *(const uint4*)(o + 0);
        *(uint4*)(As + pix*128 + (((c0+1) ^ (pix&7)) << 3)) = *(const uint4*)(o + 4);
    }
    __syncthreads();   // As complete; kvs reads done -> Cs region safe

    // proj GEMM: M=64, N=128, K=128.  8 waves = 2m x 4n.  Bs already staged.
    {
        const int l15 = lane & 15, quad = lane >> 4;
        const int wm = (wave & 1) * 32, wn = (wave >> 1) * 32;

        f32x4 acc[2][2] = {};
#pragma unroll
        for (int ks = 0; ks < 4; ks++) {
            bf16x8 af[2], bq[2];
#pragma unroll
            for (int mt = 0; mt < 2; mt++) {
                int m = wm + mt*16 + l15;
                af[mt] = *(const bf16x8*)(As + m*128 + (((ks*4+quad) ^ (m&7)) << 3));
            }
#pragma unroll
            for (int ntl = 0; ntl < 2; ntl++) {
                int n = wn + ntl*16 + l15;
                bq[ntl] = *(const bf16x8*)(Bs + n*128 + (((ks*4+quad) ^ (n&7)) << 3));
            }
#pragma unroll
            for (int mt = 0; mt < 2; mt++)
#pragma unroll
                for (int ntl = 0; ntl < 2; ntl++)
                    acc[mt][ntl] = __builtin_amdgcn_mfma_f32_16x16x32_bf16(
                        af[mt], bq[ntl], acc[mt][ntl], 0, 0, 0);
        }

#pragma unroll
        for (int ntl = 0; ntl < 2; ntl++) {
            int nl = wn + ntl*16 + l15;
            float bv = proj_b[nl];
#pragma unroll
            for (int mt = 0; mt < 2; mt++)
#pragma unroll
                for (int r = 0; r < 4; r++) {
                    int ml = wm + mt*16 + quad*4 + r;
                    Cs[ml*128 + nl] = acc[mt][ntl][r] + bv;
                }
        }
    }
    __syncthreads();

    // epilogue: out = Cs * gate + x
    {
        int pix = tid >> 3, part = tid & 7;
        int gi = ti0 + (pix >> 3), gj = tj0 + (pix & 7);
        size_t gr = (size_t)(((b << 6) + gi) << 6) + gj;
        float gv = gate[gr];
        const float* xr = x + gr*128 + part*16;
        float* orow = out + gr*128 + part*16;
#pragma unroll
        for (int q = 0; q < 4; q++) {
            float4 cv = *(const float4*)(Cs + pix*128 + part*16 + q*4);
            float4 xv = *(const float4*)(xr + q*4);
            float4 o;
            o.x = cv.x * gv + xv.x; o.y = cv.y * gv + xv.y;
            o.z = cv.z * gv + xv.z; o.w = cv.w * gv + xv.w;
            *(float4*)(orow + q*4) = o;
        }
    }
}

// ---------------------------------------------------------------------------
extern "C" void kernel_launch(void* const* d_in, const int* in_sizes, int n_in,
                              void* d_out, int out_size, void* d_ws, size_t ws_size,
                              hipStream_t stream)
{
    const float* x      = (const float*)d_in[0];
    const float* qkv_w  = (const float*)d_in[1];
    const float* qkv_b  = (const float*)d_in[2];
    const float* proj_w = (const float*)d_in[3];
    const float* proj_b = (const float*)d_in[4];
    const float* rpb    = (const float*)d_in[5];
    const float* g1_w   = (const float*)d_in[6];
    const float* g1_b   = (const float*)d_in[7];
    const float* g2_w   = (const float*)d_in[8];
    const float* g2_b   = (const float*)d_in[9];
    float* out = (float*)d_out;

    float* ws        = (float*)d_ws;
    float* gate      = ws;                          // 16384 f32
    float* bias_ext  = gate + 16384;                // 448 f32
    unsigned short* wT    = (unsigned short*)(bias_ext + 448);  // 448*128
    unsigned short* pT    = wT + 57344;             // 128*128
    unsigned short* qkvb  = pT + 16384;             // 16384*384 bf16

    (void)in_sizes; (void)n_in; (void)out_size; (void)ws_size;

    // one-time host-only opt-in for 155.3 KB dynamic LDS (capture-safe)
    static int lds_ok = -1;
    if (lds_ok < 0) {
        hipError_t ae = hipFuncSetAttribute(
            (const void*)attn_proj,
            hipFuncAttributeMaxDynamicSharedMemorySize, ATTN_PROJ_LDS);
        lds_ok = (ae == hipSuccess) ? 1 : 0;
    }

    prep_kernel<<<73, 256, 0, stream>>>(qkv_w, g1_w, qkv_b, g1_b, proj_w,
                                        wT, pT, bias_ext);
    gemm_qkvh_fused<<<dim3(2, 256), 256, 0, stream>>>(x, wT, bias_ext,
                                                      g2_w, g2_b, qkvb, gate);
    attn_proj<<<256, 512, ATTN_PROJ_LDS, stream>>>(qkvb, rpb, pT, proj_b,
                                                   gate, x, out);
}